// Round 2
// baseline (211.171 us; speedup 1.0000x reference)
//
#include <hip/hip_runtime.h>

// Fold / col2im: x[16, 9, 512, 512] f32 -> out[16, 1, 512, 512] f32
// out[b,p,q] = sum_{i,j in 0..2} x[b, i*3+j, p+1-i, q+1-j]  (OOB taps = 0)
//
// Memory-bound: 151 MB read + 17 MB write, each input element used once.
// Layout: one wave (64 lanes) per image row; lane l owns columns 8l..8l+7.
// All global loads are 16B-aligned dwordx4; the +/-1 column shifts are
// resolved in-register plus two __shfl per channel-triple. Wave edges align
// with true image boundaries, so there is no divergent fallback path.

constexpr int B = 16;
constexpr int C = 9;
constexpr int H = 512;
constexpr int W = 512;

typedef float f4 __attribute__((ext_vector_type(4)));

__global__ __launch_bounds__(256) void fold_kernel(const float* __restrict__ x,
                                                   float* __restrict__ out) {
    const int gtid = blockIdx.x * blockDim.x + threadIdx.x;
    const int row  = gtid >> 6;          // global wave id = (b*H + p)
    const int lane = threadIdx.x & 63;
    const int p = row & (H - 1);
    const int b = row >> 9;              // row / H
    const int q0 = lane * 8;             // first output column of this lane

    const size_t plane = (size_t)H * W;
    const float* xb = x + (size_t)b * C * plane;

    float acc0 = 0.f, acc1 = 0.f, acc2 = 0.f, acc3 = 0.f;
    float acc4 = 0.f, acc5 = 0.f, acc6 = 0.f, acc7 = 0.f;

#pragma unroll
    for (int i = 0; i < 3; ++i) {
        const int r = p + 1 - i;
        if (r < 0 || r >= H) continue;   // wave-uniform: padded row
        const float* base = xb + (size_t)(3 * i) * plane + (size_t)r * W + q0;

        const f4 a0 = *reinterpret_cast<const f4*>(base);              // ch 3i+0, cols q0..q0+3
        const f4 a1 = *reinterpret_cast<const f4*>(base + 4);          //          cols q0+4..q0+7
        const f4 b0 = *reinterpret_cast<const f4*>(base + plane);      // ch 3i+1
        const f4 b1 = *reinterpret_cast<const f4*>(base + plane + 4);
        const f4 c0 = *reinterpret_cast<const f4*>(base + 2 * plane);  // ch 3i+2
        const f4 c1 = *reinterpret_cast<const f4*>(base + 2 * plane + 4);

        // j=1: out[q] += x[q]  (aligned)
        acc0 += b0.x; acc1 += b0.y; acc2 += b0.z; acc3 += b0.w;
        acc4 += b1.x; acc5 += b1.y; acc6 += b1.z; acc7 += b1.w;

        // j=0: out[q] += x[q+1]  (shift left by one)
        acc0 += a0.y; acc1 += a0.z; acc2 += a0.w; acc3 += a1.x;
        acc4 += a1.y; acc5 += a1.z; acc6 += a1.w;
        const float nx = __shfl_down(a0.x, 1);   // lane+1's col q0+8
        acc7 += (lane == 63) ? 0.f : nx;         // col 512 -> pad

        // j=2: out[q] += x[q-1]  (shift right by one)
        const float pw = __shfl_up(c1.w, 1);     // lane-1's col q0-1
        acc0 += (lane == 0) ? 0.f : pw;          // col -1 -> pad
        acc1 += c0.x; acc2 += c0.y; acc3 += c0.z; acc4 += c0.w;
        acc5 += c1.x; acc6 += c1.y; acc7 += c1.z;
    }

    float* orow = out + (size_t)row * W + q0;    // 32B aligned
    f4 o0; o0.x = acc0; o0.y = acc1; o0.z = acc2; o0.w = acc3;
    f4 o1; o1.x = acc4; o1.y = acc5; o1.z = acc6; o1.w = acc7;
    *reinterpret_cast<f4*>(orow)     = o0;
    *reinterpret_cast<f4*>(orow + 4) = o1;
}

extern "C" void kernel_launch(void* const* d_in, const int* in_sizes, int n_in,
                              void* d_out, int out_size, void* d_ws, size_t ws_size,
                              hipStream_t stream) {
    const float* x = (const float*)d_in[0];
    float* out = (float*)d_out;
    const int n_waves  = B * H;                 // 8192 waves, one per row
    const int block    = 256;                   // 4 waves/block
    const int grid     = n_waves * 64 / block;  // 2048 blocks
    fold_kernel<<<grid, block, 0, stream>>>(x, out);
}